// Round 1
// baseline (109.721 us; speedup 1.0000x reference)
//
#include <hip/hip_runtime.h>

#define NB 1024      // num 4x4 blocks
#define DD 4096      // feature dim = NB * 4
#define EPS 1e-5f

// One thread per block-index b. Computes Q_b = (I - S) * inv((1+eps)I + S)
// in registers once, then streams rows: out[n,b,:] = Q_b @ x[n,b,:].
__global__ __launch_bounds__(256) void oft_apply_kernel(
    const float4* __restrict__ x4,
    const float* __restrict__ oft_r,
    float4* __restrict__ out4,
    int nrows)
{
    const int b = blockIdx.x * 256 + threadIdx.x;   // 0..NB-1 (gridDim.x = NB/256)

    // ---- load R_b (row-major 4x4) ----
    const float4* Rb = reinterpret_cast<const float4*>(oft_r + (size_t)b * 16);
    float R[16];
    #pragma unroll
    for (int k = 0; k < 4; ++k) {
        float4 v = Rb[k];
        R[4*k+0] = v.x; R[4*k+1] = v.y; R[4*k+2] = v.z; R[4*k+3] = v.w;
    }

    // ---- S = R - R^T ;  A = (1+eps)I + S ----
    float m[16];
    #pragma unroll
    for (int i = 0; i < 4; ++i)
        #pragma unroll
        for (int j = 0; j < 4; ++j) {
            float s = R[4*i+j] - R[4*j+i];
            m[4*i+j] = s + ((i == j) ? (1.0f + EPS) : 0.0f);
        }

    // ---- inv(A) via adjugate (A is near-identity, well conditioned) ----
    float inv[16];
    inv[0]  =  m[5]*m[10]*m[15] - m[5]*m[11]*m[14] - m[9]*m[6]*m[15] + m[9]*m[7]*m[14] + m[13]*m[6]*m[11] - m[13]*m[7]*m[10];
    inv[4]  = -m[4]*m[10]*m[15] + m[4]*m[11]*m[14] + m[8]*m[6]*m[15] - m[8]*m[7]*m[14] - m[12]*m[6]*m[11] + m[12]*m[7]*m[10];
    inv[8]  =  m[4]*m[9]*m[15]  - m[4]*m[11]*m[13] - m[8]*m[5]*m[15] + m[8]*m[7]*m[13] + m[12]*m[5]*m[11] - m[12]*m[7]*m[9];
    inv[12] = -m[4]*m[9]*m[14]  + m[4]*m[10]*m[13] + m[8]*m[5]*m[14] - m[8]*m[6]*m[13] - m[12]*m[5]*m[10] + m[12]*m[6]*m[9];
    inv[1]  = -m[1]*m[10]*m[15] + m[1]*m[11]*m[14] + m[9]*m[2]*m[15] - m[9]*m[3]*m[14] - m[13]*m[2]*m[11] + m[13]*m[3]*m[10];
    inv[5]  =  m[0]*m[10]*m[15] - m[0]*m[11]*m[14] - m[8]*m[2]*m[15] + m[8]*m[3]*m[14] + m[12]*m[2]*m[11] - m[12]*m[3]*m[10];
    inv[9]  = -m[0]*m[9]*m[15]  + m[0]*m[11]*m[13] + m[8]*m[1]*m[15] - m[8]*m[3]*m[13] - m[12]*m[1]*m[11] + m[12]*m[3]*m[9];
    inv[13] =  m[0]*m[9]*m[14]  - m[0]*m[10]*m[13] - m[8]*m[1]*m[14] + m[8]*m[2]*m[13] + m[12]*m[1]*m[10] - m[12]*m[2]*m[9];
    inv[2]  =  m[1]*m[6]*m[15]  - m[1]*m[7]*m[14]  - m[5]*m[2]*m[15] + m[5]*m[3]*m[14] + m[13]*m[2]*m[7]  - m[13]*m[3]*m[6];
    inv[6]  = -m[0]*m[6]*m[15]  + m[0]*m[7]*m[14]  + m[4]*m[2]*m[15] - m[4]*m[3]*m[14] - m[12]*m[2]*m[7]  + m[12]*m[3]*m[6];
    inv[10] =  m[0]*m[5]*m[15]  - m[0]*m[7]*m[13]  - m[4]*m[1]*m[15] + m[4]*m[3]*m[13] + m[12]*m[1]*m[7]  - m[12]*m[3]*m[5];
    inv[14] = -m[0]*m[5]*m[14]  + m[0]*m[6]*m[13]  + m[4]*m[1]*m[14] - m[4]*m[2]*m[13] - m[12]*m[1]*m[6]  + m[12]*m[2]*m[5];
    inv[3]  = -m[1]*m[6]*m[11]  + m[1]*m[7]*m[10]  + m[5]*m[2]*m[11] - m[5]*m[3]*m[10] - m[9]*m[2]*m[7]   + m[9]*m[3]*m[6];
    inv[7]  =  m[0]*m[6]*m[11]  - m[0]*m[7]*m[10]  - m[4]*m[2]*m[11] + m[4]*m[3]*m[10] + m[8]*m[2]*m[7]   - m[8]*m[3]*m[6];
    inv[11] = -m[0]*m[5]*m[11]  + m[0]*m[7]*m[9]   + m[4]*m[1]*m[11] - m[4]*m[3]*m[9]  - m[8]*m[1]*m[7]   + m[8]*m[3]*m[5];
    inv[15] =  m[0]*m[5]*m[10]  - m[0]*m[6]*m[9]   - m[4]*m[1]*m[10] + m[4]*m[2]*m[9]  + m[8]*m[1]*m[6]   - m[8]*m[2]*m[5];

    float det = m[0]*inv[0] + m[1]*inv[4] + m[2]*inv[8] + m[3]*inv[12];
    float invdet = 1.0f / det;
    #pragma unroll
    for (int k = 0; k < 16; ++k) inv[k] *= invdet;

    // ---- Q = (I - S) @ inv(A) ;  note (I-S)[j][k] = (j==k) - S[j][k]
    //      S[j][k] = m[4j+k] - (j==k)(1+eps)  =>  (I-S)[j][k] = 2*(j==k)(... careful) ----
    // Recompute S directly to keep it simple:
    float Q[4][4];
    #pragma unroll
    for (int j = 0; j < 4; ++j)
        #pragma unroll
        for (int i = 0; i < 4; ++i) {
            float acc = 0.0f;
            #pragma unroll
            for (int k = 0; k < 4; ++k) {
                float s_jk = R[4*j+k] - R[4*k+j];
                float b_jk = ((j == k) ? 1.0f : 0.0f) - s_jk;
                acc += b_jk * inv[4*k+i];
            }
            Q[j][i] = acc;
        }

    // ---- stream rows: y = Q_b @ x  (out[n,b,j] = sum_i Q[j][i]*x[n,b,i]) ----
    for (int n = blockIdx.y; n < nrows; n += gridDim.y) {
        const size_t idx = (size_t)n * (DD / 4) + b;
        float4 v = x4[idx];
        float4 y;
        y.x = Q[0][0]*v.x + Q[0][1]*v.y + Q[0][2]*v.z + Q[0][3]*v.w;
        y.y = Q[1][0]*v.x + Q[1][1]*v.y + Q[1][2]*v.z + Q[1][3]*v.w;
        y.z = Q[2][0]*v.x + Q[2][1]*v.y + Q[2][2]*v.z + Q[2][3]*v.w;
        y.w = Q[3][0]*v.x + Q[3][1]*v.y + Q[3][2]*v.z + Q[3][3]*v.w;
        out4[idx] = y;
    }
}

extern "C" void kernel_launch(void* const* d_in, const int* in_sizes, int n_in,
                              void* d_out, int out_size, void* d_ws, size_t ws_size,
                              hipStream_t stream) {
    const float* x     = (const float*)d_in[0];   // [4,4096,4096] fp32
    const float* oft_r = (const float*)d_in[1];   // [1024,4,4] fp32
    float* out = (float*)d_out;

    const int nrows = in_sizes[0] / DD;           // 16384

    dim3 block(256, 1, 1);
    dim3 grid(NB / 256, 512, 1);                  // 4 x 512 = 2048 WGs
    oft_apply_kernel<<<grid, block, 0, stream>>>(
        reinterpret_cast<const float4*>(x), oft_r,
        reinterpret_cast<float4*>(out), nrows);
}